// Round 6
// baseline (260.246 us; speedup 1.0000x reference)
//
#include <hip/hip_runtime.h>

#define B_  256
#define T_  256
#define S_  20
#define U1  32
#define G1  128   // 4*U1
#define U2  24
#define G2  96    // 4*U2

typedef __attribute__((ext_vector_type(8))) short short8;   // 8 bf16 = 4 VGPRs
typedef __attribute__((ext_vector_type(4))) float f32x4;    // MFMA acc

__device__ __forceinline__ float fast_rcp(float x) { return __builtin_amdgcn_rcpf(x); }
__device__ __forceinline__ float sigmoidf_(float x) { return fast_rcp(1.0f + __expf(-x)); }
__device__ __forceinline__ float tanhf_fast(float x) { return 1.0f - 2.0f * fast_rcp(1.0f + __expf(2.0f * x)); }

__device__ __forceinline__ unsigned short f2bf(float a) {
    unsigned int u = __float_as_uint(a);
    u += 0x7FFFu + ((u >> 16) & 1u);
    return (unsigned short)(u >> 16);
}
__device__ __forceinline__ unsigned int pack2bf(float a, float b) {
    unsigned int ua = __float_as_uint(a); ua += 0x7FFFu + ((ua >> 16) & 1u);
    unsigned int ub = __float_as_uint(b); ub += 0x7FFFu + ((ub >> 16) & 1u);
    return (ua >> 16) | (ub & 0xFFFF0000u);
}
union frag_u { short8 v; unsigned int u[4]; };

// Pre-swizzle Ui/Wo into MFMA B-fragment order (bf16 packed pairs), so the
// inner kernel loads its fragments with 8 coalesced dwordx4 instead of 64
// scattered dword loads interleaved with packing (32 serialized vmcnt waits).
__global__ void prep_frags(const float* __restrict__ Ui, const float* __restrict__ Wo,
                           unsigned int* __restrict__ UiF, unsigned int* __restrict__ WoF) {
    const int lane = threadIdx.x;     // 64
    const int q = lane >> 4, n = lane & 15;
#pragma unroll
    for (int tt = 0; tt < 8; ++tt)
#pragma unroll
        for (int k2 = 0; k2 < 4; ++k2) {
            const float e0 = Ui[(8 * q + 2 * k2) * G1 + 16 * tt + n];
            const float e1 = Ui[(8 * q + 2 * k2 + 1) * G1 + 16 * tt + n];
            UiF[(tt * 64 + lane) * 4 + k2] = pack2bf(e0, e1);
        }
#pragma unroll
    for (int tt = 0; tt < 6; ++tt)
#pragma unroll
        for (int k2 = 0; k2 < 4; ++k2) {
            const float e0 = Wo[(8 * q + 2 * k2) * G2 + 16 * tt + n];
            const float e1 = Wo[(8 * q + 2 * k2 + 1) * G2 + 16 * tt + n];
            WoF[(tt * 64 + lane) * 4 + k2] = pack2bf(e0, e1);
        }
}

// Inner LSTM via MFMA (bf16 inputs, fp32 accumulate). One wave = 16 rows x 32
// units; Z = H @ Ui as 8x mfma_16x16x32_bf16 per step. Fragments loaded once
// (coalesced, asm-pinned so the compiler can't sink the loads into the loop).
// x-tile (320 contiguous floats) staged to per-wave LDS once: the 20-step
// loop touches NO global memory. h round-trips per-wave LDS; no barriers.
template <bool WRITE_P>
__global__ __launch_bounds__(256, 2) void inner_kernel(
    const float* __restrict__ x,        // [B*T*S]
    const int*   __restrict__ lengths,  // [B]
    const float* __restrict__ Wi,       // [G1]
    const float* __restrict__ bi,       // [G1]
    const uint4* __restrict__ UiF,      // [8*64] swizzled fragments
    const uint4* __restrict__ WoF,      // [6*64]
    const float* __restrict__ bo,       // [G2]
    float* __restrict__ outbuf)         // P [B*T*G2] or feats [B*T*U1]
{
    __shared__ float xs[4][320];                // per-wave x tile
    __shared__ unsigned short hbb[4][16][40];   // per-wave h tile (bf16)
    const int lane = threadIdx.x & 63;
    const int w = __builtin_amdgcn_readfirstlane((int)(threadIdx.x >> 6));
    const int q = lane >> 4;
    const int n = lane & 15;
    const int tile = blockIdx.x & 3;
    const int b = blockIdx.x >> 2;
    const int len = lengths[b];
    const int wt0 = tile * 64 + w * 16;
    if (wt0 >= len) return;                     // wave-uniform exit, no barriers

    // stage x tile: rows wt0..wt0+15 = 320 consecutive floats, 5 coalesced loads
    const float* xg = x + (size_t)(b * T_ + wt0) * S_;
#pragma unroll
    for (int i = 0; i < 5; ++i) xs[w][64 * i + lane] = xg[64 * i + lane];

    // Ui fragments: 8 coalesced dwordx4; asm pins values in VGPRs
    frag_u Bui[8];
#pragma unroll
    for (int tt = 0; tt < 8; ++tt) {
        uint4 v = UiF[tt * 64 + lane];
        asm volatile("" : "+v"(v.x), "+v"(v.y), "+v"(v.z), "+v"(v.w));
        Bui[tt].u[0] = v.x; Bui[tt].u[1] = v.y; Bui[tt].u[2] = v.z; Bui[tt].u[3] = v.w;
    }
    float bi_l[8], Wi_l[8];
#pragma unroll
    for (int tt = 0; tt < 8; ++tt) {
        float bv = bi[16 * tt + n], wv = Wi[16 * tt + n];
        asm volatile("" : "+v"(bv), "+v"(wv));
        bi_l[tt] = bv; Wi_l[tt] = wv;
    }

    float c[2][4];
#pragma unroll
    for (int uh = 0; uh < 2; ++uh)
#pragma unroll
        for (int r = 0; r < 4; ++r) c[uh][r] = 0.0f;

    float xc[4], xnx[4];
#pragma unroll
    for (int r = 0; r < 4; ++r) xc[r] = xs[w][(4 * q + r) * S_];

#pragma unroll 1
    for (int s = 0; s < S_; ++s) {
        const int sn = (s + 1 < S_) ? s + 1 : S_ - 1;
#pragma unroll
        for (int r = 0; r < 4; ++r) xnx[r] = xs[w][(4 * q + r) * S_ + sn];

        f32x4 acc[8];
#pragma unroll
        for (int tt = 0; tt < 8; ++tt)
#pragma unroll
            for (int r = 0; r < 4; ++r)
                acc[tt][r] = bi_l[tt] + xc[r] * Wi_l[tt];

        if (s > 0) {   // h==0 at s==0 (uniform)
            const short8 A = *(const short8*)&hbb[w][n][8 * q];  // ds_read_b128
#pragma unroll
            for (int tt = 0; tt < 8; ++tt)
                acc[tt] = __builtin_amdgcn_mfma_f32_16x16x32_bf16(A, Bui[tt].v, acc[tt], 0, 0, 0);
        }

#pragma unroll
        for (int uh = 0; uh < 2; ++uh)
#pragma unroll
            for (int r = 0; r < 4; ++r) {
                const float iv = sigmoidf_(acc[0 + uh][r]);
                const float fv = sigmoidf_(acc[2 + uh][r]);
                const float gv = tanhf_fast(acc[4 + uh][r]);
                const float ov = sigmoidf_(acc[6 + uh][r]);
                c[uh][r] = fv * c[uh][r] + iv * gv;
                hbb[w][4 * q + r][n + 16 * uh] = f2bf(ov * tanhf_fast(c[uh][r]));
            }
#pragma unroll
        for (int r = 0; r < 4; ++r) xc[r] = xnx[r];
    }

    if constexpr (WRITE_P) {
        frag_u Bwo[6];
#pragma unroll
        for (int tt = 0; tt < 6; ++tt) {
            uint4 v = WoF[tt * 64 + lane];
            Bwo[tt].u[0] = v.x; Bwo[tt].u[1] = v.y; Bwo[tt].u[2] = v.z; Bwo[tt].u[3] = v.w;
        }
        const short8 A = *(const short8*)&hbb[w][n][8 * q];
        f32x4 accp[6];
#pragma unroll
        for (int tt = 0; tt < 6; ++tt) {
            const float bv = bo[16 * tt + n];
#pragma unroll
            for (int r = 0; r < 4; ++r) accp[tt][r] = bv;
            accp[tt] = __builtin_amdgcn_mfma_f32_16x16x32_bf16(A, Bwo[tt].v, accp[tt], 0, 0, 0);
        }
#pragma unroll
        for (int r = 0; r < 4; ++r) {
            const int t_row = wt0 + 4 * q + r;
            if (t_row < len) {
                float* Pr = outbuf + (size_t)(b * T_ + t_row) * G2 + n;
#pragma unroll
                for (int tt = 0; tt < 6; ++tt) Pr[16 * tt] = accp[tt][r];
            }
        }
    } else {
#pragma unroll
        for (int r = 0; r < 4; ++r) {
            const int t_row = wt0 + 4 * q + r;
            if (t_row < len) {
                float* Fr = outbuf + (size_t)(b * T_ + t_row) * U1;
#pragma unroll
                for (int uh = 0; uh < 2; ++uh)
                    Fr[n + 16 * uh] = __uint_as_float((unsigned)hbb[w][4 * q + r][n + 16 * uh] << 16);
            }
        }
    }
}

// Outer LSTM + head: 1 wave/seq, lane u<24 owns unit u (4 gates local).
// wu pinned in VGPRs via asm (R5: VGPR=68 + WRITE_SIZE=8KB proves the
// compiler re-loaded the 96 weights from L2 EVERY step = 430 cyc/step).
// P staged through double-buffered LDS in 32-step chunks (vmcnt wait lands
// once per chunk, hidden under 32 steps of compute); next LDS row
// prefetched one step early (hides ds_read latency). readlane h-broadcast.
__global__ __launch_bounds__(64, 1) void outer_kernel_p(
    const float* __restrict__ P,        // [B*T*G2]
    const int*   __restrict__ lengths,  // [B]
    const float* __restrict__ Uo,       // [U2*G2]
    const float* __restrict__ Wd,       // [U2]
    const float* __restrict__ bd,       // [1]
    float* __restrict__ out)            // [B]
{
    __shared__ float pl[2][32 * G2];    // 24 KB
    const int b = blockIdx.x;
    const int lane = threadIdx.x;
    const int u = (lane < U2) ? lane : U2 - 1;

    float wu[4][U2];
#pragma unroll
    for (int g = 0; g < 4; ++g)
#pragma unroll
        for (int k = 0; k < U2; ++k) {
            float v = Uo[k * G2 + g * U2 + u];
            asm volatile("" : "+v"(v));     // pin: forbid loop-sinking
            wu[g][k] = v;
        }

    const int len = lengths[b];              // >= 1
    const float* Pb = P + (size_t)b * T_ * G2;

    // stage chunk 0
    float4 st[12];
    {
        const float4* gp = (const float4*)Pb;
#pragma unroll
        for (int i = 0; i < 12; ++i) st[i] = gp[64 * i + lane];
        float4* lp = (float4*)&pl[0][0];
#pragma unroll
        for (int i = 0; i < 12; ++i) lp[64 * i + lane] = st[i];
    }

    const int nch = (len + 31) >> 5;
    float cu = 0.0f, hu = 0.0f;

#pragma unroll 1
    for (int ch = 0; ch < nch; ++ch) {
        if (ch + 1 < nch) {                  // issue next chunk's global loads
            const float4* gp = (const float4*)(Pb + (size_t)(ch + 1) * 32 * G2);
#pragma unroll
            for (int i = 0; i < 12; ++i) st[i] = gp[64 * i + lane];
        }
        const int pb = ch & 1;
        const int rem = len - ch * 32;
        const int tmax = (rem < 32) ? rem : 32;

        float pr[4];                         // row 0 of this chunk
#pragma unroll
        for (int g = 0; g < 4; ++g) pr[g] = pl[pb][g * U2 + u];

#pragma unroll 1
        for (int tt = 0; tt < tmax; ++tt) {
            const int rn = (tt + 1 < 32) ? (tt + 1) : 31;
            float prn[4];                    // prefetch next row from LDS
#pragma unroll
            for (int g = 0; g < 4; ++g) prn[g] = pl[pb][rn * G2 + g * U2 + u];

            float z0[4], z1[4];
#pragma unroll
            for (int g = 0; g < 4; ++g) { z0[g] = pr[g]; z1[g] = 0.0f; }

            if (ch * 32 + tt > 0) {          // uniform; h==0 at t==0
#pragma unroll
                for (int k = 0; k < U2; ++k) {
                    const float hk = __int_as_float(
                        __builtin_amdgcn_readlane(__float_as_int(hu), k));
#pragma unroll
                    for (int g = 0; g < 4; ++g) {
                        if (k & 1) z1[g] += hk * wu[g][k];
                        else       z0[g] += hk * wu[g][k];
                    }
                }
            }

            const float ig = sigmoidf_(z0[0] + z1[0]);
            const float fg = sigmoidf_(z0[1] + z1[1]);
            const float gg = tanhf_fast(z0[2] + z1[2]);
            const float og = sigmoidf_(z0[3] + z1[3]);
            cu = fg * cu + ig * gg;
            hu = og * tanhf_fast(cu);

#pragma unroll
            for (int g = 0; g < 4; ++g) pr[g] = prn[g];
        }

        if (ch + 1 < nch) {                  // vmcnt wait here: amortized 1/chunk
            float4* lp = (float4*)&pl[(ch + 1) & 1][0];
#pragma unroll
            for (int i = 0; i < 12; ++i) lp[64 * i + lane] = st[i];
        }
    }

    float acc = bd[0];
#pragma unroll
    for (int k = 0; k < U2; ++k)
        acc += __int_as_float(__builtin_amdgcn_readlane(__float_as_int(hu), k)) * Wd[k];
    if (lane == 0) out[b] = sigmoidf_(acc);
}

// Fallback outer (feats path): per-step Wo matvec; readlane broadcast; pinned weights.
__global__ __launch_bounds__(64, 1) void outer_kernel_f(
    const float* __restrict__ feats, const int* __restrict__ lengths,
    const float* __restrict__ Wo, const float* __restrict__ Uo,
    const float* __restrict__ bo, const float* __restrict__ Wd,
    const float* __restrict__ bd, float* __restrict__ out)
{
    const int b = blockIdx.x;
    const int lane = threadIdx.x;
    const int u = (lane < U2) ? lane : U2 - 1;

    float wu[4][U2], wx[4][U1], bz[4];
#pragma unroll
    for (int g = 0; g < 4; ++g) {
        bz[g] = bo[g * U2 + u];
#pragma unroll
        for (int k = 0; k < U2; ++k) { float v = Uo[k * G2 + g * U2 + u]; asm volatile("" : "+v"(v)); wu[g][k] = v; }
#pragma unroll
        for (int k = 0; k < U1; ++k) { float v = Wo[k * G2 + g * U2 + u]; asm volatile("" : "+v"(v)); wx[g][k] = v; }
    }

    const int len = lengths[b];
    const float* Fb = feats + (size_t)b * T_ * U1;
    float cu = 0.0f, hu = 0.0f;

#pragma unroll 1
    for (int t = 0; t < len; ++t) {
        float z[4];
#pragma unroll
        for (int g = 0; g < 4; ++g) z[g] = bz[g];
        const float* Ft = Fb + (size_t)t * U1;
#pragma unroll
        for (int k = 0; k < U1; ++k) {
            const float fk = Ft[k];
#pragma unroll
            for (int g = 0; g < 4; ++g) z[g] += fk * wx[g][k];
        }
        if (t > 0) {
#pragma unroll
            for (int k = 0; k < U2; ++k) {
                const float hk = __int_as_float(__builtin_amdgcn_readlane(__float_as_int(hu), k));
#pragma unroll
                for (int g = 0; g < 4; ++g) z[g] += hk * wu[g][k];
            }
        }
        const float ig = sigmoidf_(z[0]);
        const float fg = sigmoidf_(z[1]);
        const float gg = tanhf_fast(z[2]);
        const float og = sigmoidf_(z[3]);
        cu = fg * cu + ig * gg;
        hu = og * tanhf_fast(cu);
    }

    float acc = bd[0];
#pragma unroll
    for (int k = 0; k < U2; ++k)
        acc += __int_as_float(__builtin_amdgcn_readlane(__float_as_int(hu), k)) * Wd[k];
    if (lane == 0) out[b] = sigmoidf_(acc);
}

extern "C" void kernel_launch(void* const* d_in, const int* in_sizes, int n_in,
                              void* d_out, int out_size, void* d_ws, size_t ws_size,
                              hipStream_t stream) {
    const float* x       = (const float*)d_in[0];
    const int*   lengths = (const int*)  d_in[1];
    const float* Wi      = (const float*)d_in[2];
    const float* Ui      = (const float*)d_in[3];
    const float* bi      = (const float*)d_in[4];
    const float* Wo      = (const float*)d_in[5];
    const float* Uo      = (const float*)d_in[6];
    const float* bo      = (const float*)d_in[7];
    const float* Wd      = (const float*)d_in[8];
    const float* bd      = (const float*)d_in[9];
    float* out = (float*)d_out;

    // ws layout: [UiF 8KB][WoF 6KB][pad to 16KB][P or feats]
    unsigned int* UiF = (unsigned int*)d_ws;
    unsigned int* WoF = UiF + 2048;
    float* data = (float*)((char*)d_ws + 16384);
    const size_t P_BYTES = (size_t)B_ * T_ * G2 * sizeof(float);   // 25.2 MB

    prep_frags<<<dim3(1), dim3(64), 0, stream>>>(Ui, Wo, UiF, WoF);

    if (ws_size >= 16384 + P_BYTES) {
        inner_kernel<true><<<dim3(B_ * T_ / 64), dim3(256), 0, stream>>>(
            x, lengths, Wi, bi, (const uint4*)UiF, (const uint4*)WoF, bo, data);
        outer_kernel_p<<<dim3(B_), dim3(64), 0, stream>>>(
            data, lengths, Uo, Wd, bd, out);
    } else {
        inner_kernel<false><<<dim3(B_ * T_ / 64), dim3(256), 0, stream>>>(
            x, lengths, Wi, bi, (const uint4*)UiF, (const uint4*)WoF, bo, data);
        outer_kernel_f<<<dim3(B_), dim3(64), 0, stream>>>(
            data, lengths, Wo, Uo, bo, Wd, bd, out);
    }
}

// Round 7
// 199.358 us; speedup vs baseline: 1.3054x; 1.3054x over previous
//
#include <hip/hip_runtime.h>

#define B_  256
#define T_  256
#define S_  20
#define U1  32
#define G1  128   // 4*U1
#define U2  24
#define G2  96    // 4*U2

typedef __attribute__((ext_vector_type(8))) short short8;   // 8 bf16 = 4 VGPRs
typedef __attribute__((ext_vector_type(4))) float f32x4;    // MFMA acc

// Raw-hardware activations: v_exp_f32 computes 2^x, so pre-scale by log2(e).
// __expf was lowering to a multi-inst ocml sequence (~10+ insts incl fixups);
// the ~60cyc dependent exp chains dominated EVERY kernel variant R1-R6.
__device__ __forceinline__ float sigmoidf_(float x) {
    return __builtin_amdgcn_rcpf(1.0f + __builtin_amdgcn_exp2f(x * -1.44269504f));
}
__device__ __forceinline__ float tanhf_fast(float x) {   // 1 - 2/(1+e^{2x})
    return 1.0f - 2.0f * __builtin_amdgcn_rcpf(1.0f + __builtin_amdgcn_exp2f(x * 2.88539008f));
}

__device__ __forceinline__ unsigned short f2bf(float a) {
    unsigned int u = __float_as_uint(a);
    u += 0x7FFFu + ((u >> 16) & 1u);
    return (unsigned short)(u >> 16);
}
__device__ __forceinline__ unsigned int pack2bf(float a, float b) {
    unsigned int ua = __float_as_uint(a); ua += 0x7FFFu + ((ua >> 16) & 1u);
    unsigned int ub = __float_as_uint(b); ub += 0x7FFFu + ((ub >> 16) & 1u);
    return (ua >> 16) | (ub & 0xFFFF0000u);
}
union frag_u { short8 v; unsigned int u[4]; };

// Pre-swizzle Ui/Wo into MFMA B-fragment order (bf16 packed pairs).
__global__ void prep_frags(const float* __restrict__ Ui, const float* __restrict__ Wo,
                           unsigned int* __restrict__ UiF, unsigned int* __restrict__ WoF) {
    const int lane = threadIdx.x;     // 64
    const int q = lane >> 4, n = lane & 15;
#pragma unroll
    for (int tt = 0; tt < 8; ++tt)
#pragma unroll
        for (int k2 = 0; k2 < 4; ++k2) {
            const float e0 = Ui[(8 * q + 2 * k2) * G1 + 16 * tt + n];
            const float e1 = Ui[(8 * q + 2 * k2 + 1) * G1 + 16 * tt + n];
            UiF[(tt * 64 + lane) * 4 + k2] = pack2bf(e0, e1);
        }
#pragma unroll
    for (int tt = 0; tt < 6; ++tt)
#pragma unroll
        for (int k2 = 0; k2 < 4; ++k2) {
            const float e0 = Wo[(8 * q + 2 * k2) * G2 + 16 * tt + n];
            const float e1 = Wo[(8 * q + 2 * k2 + 1) * G2 + 16 * tt + n];
            WoF[(tt * 64 + lane) * 4 + k2] = pack2bf(e0, e1);
        }
}

// Inner LSTM via MFMA (bf16 in, fp32 acc). One wave = 16 t-rows x 32 units;
// Z = H @ Ui as 8x mfma_16x16x32_bf16/step; fragments resident in VGPRs.
// x staged to per-wave LDS; h round-trips per-wave LDS; no barriers.
template <bool WRITE_P>
__global__ __launch_bounds__(256, 2) void inner_kernel(
    const float* __restrict__ x, const int* __restrict__ lengths,
    const float* __restrict__ Wi, const float* __restrict__ bi,
    const uint4* __restrict__ UiF, const uint4* __restrict__ WoF,
    const float* __restrict__ bo, float* __restrict__ outbuf)
{
    __shared__ float xs[4][320];
    __shared__ unsigned short hbb[4][16][40];
    const int lane = threadIdx.x & 63;
    const int w = __builtin_amdgcn_readfirstlane((int)(threadIdx.x >> 6));
    const int q = lane >> 4;
    const int n = lane & 15;
    const int tile = blockIdx.x & 3;
    const int b = blockIdx.x >> 2;
    const int len = lengths[b];
    const int wt0 = tile * 64 + w * 16;
    if (wt0 >= len) return;                     // wave-uniform exit, no barriers

    const float* xg = x + (size_t)(b * T_ + wt0) * S_;
#pragma unroll
    for (int i = 0; i < 5; ++i) xs[w][64 * i + lane] = xg[64 * i + lane];

    frag_u Bui[8];
#pragma unroll
    for (int tt = 0; tt < 8; ++tt) {
        uint4 v = UiF[tt * 64 + lane];
        Bui[tt].u[0] = v.x; Bui[tt].u[1] = v.y; Bui[tt].u[2] = v.z; Bui[tt].u[3] = v.w;
    }
    float bi_l[8], Wi_l[8];
#pragma unroll
    for (int tt = 0; tt < 8; ++tt) { bi_l[tt] = bi[16 * tt + n]; Wi_l[tt] = Wi[16 * tt + n]; }

    float c[2][4];
#pragma unroll
    for (int uh = 0; uh < 2; ++uh)
#pragma unroll
        for (int r = 0; r < 4; ++r) c[uh][r] = 0.0f;

    float xc[4], xnx[4];
#pragma unroll
    for (int r = 0; r < 4; ++r) xc[r] = xs[w][(4 * q + r) * S_];

#pragma unroll 1
    for (int s = 0; s < S_; ++s) {
        const int sn = (s + 1 < S_) ? s + 1 : S_ - 1;
#pragma unroll
        for (int r = 0; r < 4; ++r) xnx[r] = xs[w][(4 * q + r) * S_ + sn];

        f32x4 acc[8];
#pragma unroll
        for (int tt = 0; tt < 8; ++tt)
#pragma unroll
            for (int r = 0; r < 4; ++r)
                acc[tt][r] = bi_l[tt] + xc[r] * Wi_l[tt];

        if (s > 0) {   // h==0 at s==0 (uniform)
            const short8 A = *(const short8*)&hbb[w][n][8 * q];  // ds_read_b128
#pragma unroll
            for (int tt = 0; tt < 8; ++tt)
                acc[tt] = __builtin_amdgcn_mfma_f32_16x16x32_bf16(A, Bui[tt].v, acc[tt], 0, 0, 0);
        }

#pragma unroll
        for (int uh = 0; uh < 2; ++uh)
#pragma unroll
            for (int r = 0; r < 4; ++r) {
                const float iv = sigmoidf_(acc[0 + uh][r]);
                const float fv = sigmoidf_(acc[2 + uh][r]);
                const float gv = tanhf_fast(acc[4 + uh][r]);
                const float ov = sigmoidf_(acc[6 + uh][r]);
                c[uh][r] = fv * c[uh][r] + iv * gv;
                hbb[w][4 * q + r][n + 16 * uh] = f2bf(ov * tanhf_fast(c[uh][r]));
            }
#pragma unroll
        for (int r = 0; r < 4; ++r) xc[r] = xnx[r];
    }

    if constexpr (WRITE_P) {
        frag_u Bwo[6];
#pragma unroll
        for (int tt = 0; tt < 6; ++tt) {
            uint4 v = WoF[tt * 64 + lane];
            Bwo[tt].u[0] = v.x; Bwo[tt].u[1] = v.y; Bwo[tt].u[2] = v.z; Bwo[tt].u[3] = v.w;
        }
        const short8 A = *(const short8*)&hbb[w][n][8 * q];
        f32x4 accp[6];
#pragma unroll
        for (int tt = 0; tt < 6; ++tt) {
            const float bv = bo[16 * tt + n];
#pragma unroll
            for (int r = 0; r < 4; ++r) accp[tt][r] = bv;
            accp[tt] = __builtin_amdgcn_mfma_f32_16x16x32_bf16(A, Bwo[tt].v, accp[tt], 0, 0, 0);
        }
#pragma unroll
        for (int r = 0; r < 4; ++r) {
            const int t_row = wt0 + 4 * q + r;
            if (t_row < len) {
                float* Pr = outbuf + (size_t)(b * T_ + t_row) * G2 + n;
#pragma unroll
                for (int tt = 0; tt < 6; ++tt) Pr[16 * tt] = accp[tt][r];
            }
        }
    } else {
#pragma unroll
        for (int r = 0; r < 4; ++r) {
            const int t_row = wt0 + 4 * q + r;
            if (t_row < len) {
                float* Fr = outbuf + (size_t)(b * T_ + t_row) * U1;
#pragma unroll
                for (int uh = 0; uh < 2; ++uh)
                    Fr[n + 16 * uh] = __uint_as_float((unsigned)hbb[w][4 * q + r][n + 16 * uh] << 16);
            }
        }
    }
}

// Outer LSTM + head: 1 wave/seq. GATE-SPLIT across wave halves: half 0
// (lanes 0-31) computes gates i,f of unit u=lane&31; half 1 computes g,o.
// Each lane holds only 48 weight VGPRs (2 gates x 24 k) -- below the
// compiler's sink/spill threshold that plagued R5 (sink, VGPR=68) and
// R6 (asm-pin -> spill, 3MB scratch). z halves exchanged with 2 shfl_xor(32);
// both halves then compute identical c/h (hu valid on lanes 0-23 for the
// uniform readlane broadcast). Ring-3 P prefetch. No LDS, no barriers.
__global__ __launch_bounds__(64, 1) void outer_kernel_p(
    const float* __restrict__ P,        // [B*T*G2]
    const int*   __restrict__ lengths,  // [B]
    const float* __restrict__ Uo,       // [U2*G2]
    const float* __restrict__ Wd,       // [U2]
    const float* __restrict__ bd,       // [1]
    float* __restrict__ out)            // [B]
{
    const int b = blockIdx.x;
    const int lane = threadIdx.x;
    const int half = lane >> 5;              // 0: gates i,f  1: gates g,o
    const int sub  = lane & 31;
    const int u    = (sub < U2) ? sub : U2 - 1;
    const int gA   = 2 * half;               // my first gate
    const int gB   = 2 * half + 1;           // my second gate

    float wA[U2], wB[U2];                    // 48 VGPRs of weights
#pragma unroll
    for (int k = 0; k < U2; ++k) {
        wA[k] = Uo[k * G2 + gA * U2 + u];
        wB[k] = Uo[k * G2 + gB * U2 + u];
    }

    const int len = lengths[b];              // >= 1
    const float* Pb = P + (size_t)b * T_ * G2;

    float cu = 0.0f, hu = 0.0f;
    // ring-3 prefetch of the two P entries this lane's gates need
    float pA[3], pB[3];
#pragma unroll
    for (int i = 0; i < 3; ++i) {
        const int ti = (i < len) ? i : len - 1;
        pA[i] = Pb[(size_t)ti * G2 + gA * U2 + u];
        pB[i] = Pb[(size_t)ti * G2 + gB * U2 + u];
    }

#pragma unroll 1
    for (int t = 0; t < len; ++t) {
        const int tn = (t + 3 < len) ? (t + 3) : (len - 1);
        const float pAn = Pb[(size_t)tn * G2 + gA * U2 + u];
        const float pBn = Pb[(size_t)tn * G2 + gB * U2 + u];

        float zA0 = pA[0], zA1 = 0.0f, zB0 = pB[0], zB1 = 0.0f;
        if (t > 0) {                         // uniform; h==0 at t==0
#pragma unroll
            for (int k = 0; k < U2; ++k) {
                const float hk = __int_as_float(
                    __builtin_amdgcn_readlane(__float_as_int(hu), k));  // uniform idx
                if (k & 1) { zA1 += hk * wA[k]; zB1 += hk * wB[k]; }
                else       { zA0 += hk * wA[k]; zB0 += hk * wB[k]; }
            }
        }
        const float zA = zA0 + zA1;          // half0: z_i ; half1: z_g
        const float zB = zB0 + zB1;          // half0: z_f ; half1: z_o
        const float oA = __shfl_xor(zA, 32); // the other half's zA
        const float oB = __shfl_xor(zB, 32);

        const float z_i = half ? oA : zA;
        const float z_f = half ? oB : zB;
        const float z_g = half ? zA : oA;
        const float z_o = half ? zB : oB;

        const float ig = sigmoidf_(z_i);
        const float fg = sigmoidf_(z_f);
        const float gg = tanhf_fast(z_g);
        const float og = sigmoidf_(z_o);
        cu = fg * cu + ig * gg;
        hu = og * tanhf_fast(cu);            // identical on both halves

        pA[0] = pA[1]; pA[1] = pA[2]; pA[2] = pAn;
        pB[0] = pB[1]; pB[1] = pB[2]; pB[2] = pBn;
    }

    float acc = bd[0];
#pragma unroll
    for (int k = 0; k < U2; ++k)
        acc += __int_as_float(__builtin_amdgcn_readlane(__float_as_int(hu), k)) * Wd[k];
    if (lane == 0) out[b] = sigmoidf_(acc);
}

// Fallback outer (feats path): per-step Wo matvec; readlane broadcast.
__global__ __launch_bounds__(64, 1) void outer_kernel_f(
    const float* __restrict__ feats, const int* __restrict__ lengths,
    const float* __restrict__ Wo, const float* __restrict__ Uo,
    const float* __restrict__ bo, const float* __restrict__ Wd,
    const float* __restrict__ bd, float* __restrict__ out)
{
    const int b = blockIdx.x;
    const int lane = threadIdx.x;
    const int u = (lane < U2) ? lane : U2 - 1;

    float wu[4][U2], wx[4][U1], bz[4];
#pragma unroll
    for (int g = 0; g < 4; ++g) {
        bz[g] = bo[g * U2 + u];
#pragma unroll
        for (int k = 0; k < U2; ++k) wu[g][k] = Uo[k * G2 + g * U2 + u];
#pragma unroll
        for (int k = 0; k < U1; ++k) wx[g][k] = Wo[k * G2 + g * U2 + u];
    }

    const int len = lengths[b];
    const float* Fb = feats + (size_t)b * T_ * U1;
    float cu = 0.0f, hu = 0.0f;

#pragma unroll 1
    for (int t = 0; t < len; ++t) {
        float z[4];
#pragma unroll
        for (int g = 0; g < 4; ++g) z[g] = bz[g];
        const float* Ft = Fb + (size_t)t * U1;
#pragma unroll
        for (int k = 0; k < U1; ++k) {
            const float fk = Ft[k];
#pragma unroll
            for (int g = 0; g < 4; ++g) z[g] += fk * wx[g][k];
        }
        if (t > 0) {
#pragma unroll
            for (int k = 0; k < U2; ++k) {
                const float hk = __int_as_float(__builtin_amdgcn_readlane(__float_as_int(hu), k));
#pragma unroll
                for (int g = 0; g < 4; ++g) z[g] += hk * wu[g][k];
            }
        }
        const float ig = sigmoidf_(z[0]);
        const float fg = sigmoidf_(z[1]);
        const float gg = tanhf_fast(z[2]);
        const float og = sigmoidf_(z[3]);
        cu = fg * cu + ig * gg;
        hu = og * tanhf_fast(cu);
    }

    float acc = bd[0];
#pragma unroll
    for (int k = 0; k < U2; ++k)
        acc += __int_as_float(__builtin_amdgcn_readlane(__float_as_int(hu), k)) * Wd[k];
    if (lane == 0) out[b] = sigmoidf_(acc);
}

extern "C" void kernel_launch(void* const* d_in, const int* in_sizes, int n_in,
                              void* d_out, int out_size, void* d_ws, size_t ws_size,
                              hipStream_t stream) {
    const float* x       = (const float*)d_in[0];
    const int*   lengths = (const int*)  d_in[1];
    const float* Wi      = (const float*)d_in[2];
    const float* Ui      = (const float*)d_in[3];
    const float* bi      = (const float*)d_in[4];
    const float* Wo      = (const float*)d_in[5];
    const float* Uo      = (const float*)d_in[6];
    const float* bo      = (const float*)d_in[7];
    const float* Wd      = (const float*)d_in[8];
    const float* bd      = (const float*)d_in[9];
    float* out = (float*)d_out;

    unsigned int* UiF = (unsigned int*)d_ws;
    unsigned int* WoF = UiF + 2048;
    float* data = (float*)((char*)d_ws + 16384);
    const size_t P_BYTES = (size_t)B_ * T_ * G2 * sizeof(float);   // 25.2 MB

    prep_frags<<<dim3(1), dim3(64), 0, stream>>>(Ui, Wo, UiF, WoF);

    if (ws_size >= 16384 + P_BYTES) {
        inner_kernel<true><<<dim3(B_ * T_ / 64), dim3(256), 0, stream>>>(
            x, lengths, Wi, bi, (const uint4*)UiF, (const uint4*)WoF, bo, data);
        outer_kernel_p<<<dim3(B_), dim3(64), 0, stream>>>(
            data, lengths, Uo, Wd, bd, out);
    } else {
        inner_kernel<false><<<dim3(B_ * T_ / 64), dim3(256), 0, stream>>>(
            x, lengths, Wi, bi, (const uint4*)UiF, (const uint4*)WoF, bo, data);
        outer_kernel_f<<<dim3(B_), dim3(64), 0, stream>>>(
            data, lengths, Wo, Uo, bo, Wd, bd, out);
    }
}

// Round 8
// 198.207 us; speedup vs baseline: 1.3130x; 1.0058x over previous
//
#include <hip/hip_runtime.h>

#define B_  256
#define T_  256
#define S_  20
#define U1  32
#define G1  128   // 4*U1
#define U2  24
#define G2  96    // 4*U2

typedef __attribute__((ext_vector_type(8))) short short8;   // 8 bf16 = 4 VGPRs
typedef __attribute__((ext_vector_type(4))) float f32x4;    // MFMA acc

// Raw-HW activations (v_exp_f32 = 2^x, pre-scaled by log2e). R7 confirmed:
// replacing ocml __expf with these took outer 134->74us.
__device__ __forceinline__ float sigmoidf_(float x) {
    return __builtin_amdgcn_rcpf(1.0f + __builtin_amdgcn_exp2f(x * -1.44269504f));
}
__device__ __forceinline__ float tanhf_fast(float x) {   // 1 - 2/(1+e^{2x})
    return 1.0f - 2.0f * __builtin_amdgcn_rcpf(1.0f + __builtin_amdgcn_exp2f(x * 2.88539008f));
}

__device__ __forceinline__ unsigned short f2bf(float a) {
    unsigned int u = __float_as_uint(a);
    u += 0x7FFFu + ((u >> 16) & 1u);
    return (unsigned short)(u >> 16);
}
__device__ __forceinline__ unsigned int pack2bf(float a, float b) {
    unsigned int ua = __float_as_uint(a); ua += 0x7FFFu + ((ua >> 16) & 1u);
    unsigned int ub = __float_as_uint(b); ub += 0x7FFFu + ((ub >> 16) & 1u);
    return (ua >> 16) | (ub & 0xFFFF0000u);
}
union frag_u { short8 v; unsigned int u[4]; };

// Pre-swizzle Ui/Wo into MFMA B-fragment order (bf16 packed pairs).
__global__ void prep_frags(const float* __restrict__ Ui, const float* __restrict__ Wo,
                           unsigned int* __restrict__ UiF, unsigned int* __restrict__ WoF) {
    const int lane = threadIdx.x;     // 64
    const int q = lane >> 4, n = lane & 15;
#pragma unroll
    for (int tt = 0; tt < 8; ++tt)
#pragma unroll
        for (int k2 = 0; k2 < 4; ++k2) {
            const float e0 = Ui[(8 * q + 2 * k2) * G1 + 16 * tt + n];
            const float e1 = Ui[(8 * q + 2 * k2 + 1) * G1 + 16 * tt + n];
            UiF[(tt * 64 + lane) * 4 + k2] = pack2bf(e0, e1);
        }
#pragma unroll
    for (int tt = 0; tt < 6; ++tt)
#pragma unroll
        for (int k2 = 0; k2 < 4; ++k2) {
            const float e0 = Wo[(8 * q + 2 * k2) * G2 + 16 * tt + n];
            const float e1 = Wo[(8 * q + 2 * k2 + 1) * G2 + 16 * tt + n];
            WoF[(tt * 64 + lane) * 4 + k2] = pack2bf(e0, e1);
        }
}

// Inner LSTM via MFMA (bf16 in, fp32 acc). One wave = 16 t-rows x 32 units.
// STEP 0 IS PEELED: the steady-state loop uses the Ui fragments
// UNCONDITIONALLY, so LICM keeps them resident in VGPRs. (R5-R7: uses were
// inside `if (s>0)` -> LLVM sank the fragment loads into the conditional ->
// per-step L2 refetch; inner plateaued ~60-110us across 3 memory-side fixes.)
template <bool WRITE_P>
__global__ __launch_bounds__(256, 2) void inner_kernel(
    const float* __restrict__ x, const int* __restrict__ lengths,
    const float* __restrict__ Wi, const float* __restrict__ bi,
    const uint4* __restrict__ UiF, const uint4* __restrict__ WoF,
    const float* __restrict__ bo, float* __restrict__ outbuf)
{
    __shared__ float xs[4][320];
    __shared__ unsigned short hbb[4][16][40];
    const int lane = threadIdx.x & 63;
    const int w = __builtin_amdgcn_readfirstlane((int)(threadIdx.x >> 6));
    const int q = lane >> 4;
    const int n = lane & 15;
    const int tile = blockIdx.x & 3;
    const int b = blockIdx.x >> 2;
    const int len = lengths[b];
    const int wt0 = tile * 64 + w * 16;
    if (wt0 >= len) return;                     // wave-uniform exit, no barriers

    // stage x tile (320 contiguous floats, 5 coalesced loads)
    const float* xg = x + (size_t)(b * T_ + wt0) * S_;
#pragma unroll
    for (int i = 0; i < 5; ++i) xs[w][64 * i + lane] = xg[64 * i + lane];

    // Ui fragments: issued here, latency overlapped by the peeled step 0
    frag_u Bui[8];
#pragma unroll
    for (int tt = 0; tt < 8; ++tt) {
        uint4 v = UiF[tt * 64 + lane];
        Bui[tt].u[0] = v.x; Bui[tt].u[1] = v.y; Bui[tt].u[2] = v.z; Bui[tt].u[3] = v.w;
    }
    float bi_l[8], Wi_l[8];
#pragma unroll
    for (int tt = 0; tt < 8; ++tt) { bi_l[tt] = bi[16 * tt + n]; Wi_l[tt] = Wi[16 * tt + n]; }

    float c[2][4];
#pragma unroll
    for (int uh = 0; uh < 2; ++uh)
#pragma unroll
        for (int r = 0; r < 4; ++r) c[uh][r] = 0.0f;

    // ---- peeled s = 0 (h == 0: no MFMA) ----
    {
        float x0[4];
#pragma unroll
        for (int r = 0; r < 4; ++r) x0[r] = xs[w][(4 * q + r) * S_];
        f32x4 acc[8];
#pragma unroll
        for (int tt = 0; tt < 8; ++tt)
#pragma unroll
            for (int r = 0; r < 4; ++r)
                acc[tt][r] = bi_l[tt] + x0[r] * Wi_l[tt];
#pragma unroll
        for (int uh = 0; uh < 2; ++uh)
#pragma unroll
            for (int r = 0; r < 4; ++r) {
                const float iv = sigmoidf_(acc[0 + uh][r]);
                const float fv = sigmoidf_(acc[2 + uh][r]);
                const float gv = tanhf_fast(acc[4 + uh][r]);
                const float ov = sigmoidf_(acc[6 + uh][r]);
                c[uh][r] = fv * c[uh][r] + iv * gv;
                hbb[w][4 * q + r][n + 16 * uh] = f2bf(ov * tanhf_fast(c[uh][r]));
            }
    }

    // ---- steady state s = 1..19: unconditional MFMA (fragments stay live) ----
    float xc[4];
#pragma unroll
    for (int r = 0; r < 4; ++r) xc[r] = xs[w][(4 * q + r) * S_ + 1];

#pragma unroll 1
    for (int s = 1; s < S_; ++s) {
        const int sn = (s + 1 < S_) ? s + 1 : S_ - 1;
        float xnx[4];
#pragma unroll
        for (int r = 0; r < 4; ++r) xnx[r] = xs[w][(4 * q + r) * S_ + sn];

        f32x4 acc[8];
#pragma unroll
        for (int tt = 0; tt < 8; ++tt)
#pragma unroll
            for (int r = 0; r < 4; ++r)
                acc[tt][r] = bi_l[tt] + xc[r] * Wi_l[tt];

        const short8 A = *(const short8*)&hbb[w][n][8 * q];  // ds_read_b128
#pragma unroll
        for (int tt = 0; tt < 8; ++tt)
            acc[tt] = __builtin_amdgcn_mfma_f32_16x16x32_bf16(A, Bui[tt].v, acc[tt], 0, 0, 0);

#pragma unroll
        for (int uh = 0; uh < 2; ++uh)
#pragma unroll
            for (int r = 0; r < 4; ++r) {
                const float iv = sigmoidf_(acc[0 + uh][r]);
                const float fv = sigmoidf_(acc[2 + uh][r]);
                const float gv = tanhf_fast(acc[4 + uh][r]);
                const float ov = sigmoidf_(acc[6 + uh][r]);
                c[uh][r] = fv * c[uh][r] + iv * gv;
                hbb[w][4 * q + r][n + 16 * uh] = f2bf(ov * tanhf_fast(c[uh][r]));
            }
#pragma unroll
        for (int r = 0; r < 4; ++r) xc[r] = xnx[r];
    }

    if constexpr (WRITE_P) {
        frag_u Bwo[6];
#pragma unroll
        for (int tt = 0; tt < 6; ++tt) {
            uint4 v = WoF[tt * 64 + lane];
            Bwo[tt].u[0] = v.x; Bwo[tt].u[1] = v.y; Bwo[tt].u[2] = v.z; Bwo[tt].u[3] = v.w;
        }
        const short8 A = *(const short8*)&hbb[w][n][8 * q];
        f32x4 accp[6];
#pragma unroll
        for (int tt = 0; tt < 6; ++tt) {
            const float bv = bo[16 * tt + n];
#pragma unroll
            for (int r = 0; r < 4; ++r) accp[tt][r] = bv;
            accp[tt] = __builtin_amdgcn_mfma_f32_16x16x32_bf16(A, Bwo[tt].v, accp[tt], 0, 0, 0);
        }
#pragma unroll
        for (int r = 0; r < 4; ++r) {
            const int t_row = wt0 + 4 * q + r;
            if (t_row < len) {
                float* Pr = outbuf + (size_t)(b * T_ + t_row) * G2 + n;
#pragma unroll
                for (int tt = 0; tt < 6; ++tt) Pr[16 * tt] = accp[tt][r];
            }
        }
    } else {
#pragma unroll
        for (int r = 0; r < 4; ++r) {
            const int t_row = wt0 + 4 * q + r;
            if (t_row < len) {
                float* Fr = outbuf + (size_t)(b * T_ + t_row) * U1;
#pragma unroll
                for (int uh = 0; uh < 2; ++uh)
                    Fr[n + 16 * uh] = __uint_as_float((unsigned)hbb[w][4 * q + r][n + 16 * uh] << 16);
            }
        }
    }
}

// Outer LSTM + head: 1 wave/seq, gate-split across wave halves (half 0:
// gates i,f; half 1: g,o; each lane 48 weight VGPRs). T=0 IS PEELED so the
// steady-state loop uses wA/wB unconditionally -> loads stay hoisted &
// resident (R7: uses inside `if(t>0)` -> sunk, VGPR=36, per-step L2 refetch).
// z halves combined with 2 shfl_xor(32); readlane h-broadcast (uniform idx).
__global__ __launch_bounds__(64, 1) void outer_kernel_p(
    const float* __restrict__ P,        // [B*T*G2]
    const int*   __restrict__ lengths,  // [B]
    const float* __restrict__ Uo,       // [U2*G2]
    const float* __restrict__ Wd,       // [U2]
    const float* __restrict__ bd,       // [1]
    float* __restrict__ out)            // [B]
{
    const int b = blockIdx.x;
    const int lane = threadIdx.x;
    const int half = lane >> 5;              // 0: gates i,f  1: gates g,o
    const int sub  = lane & 31;
    const int u    = (sub < U2) ? sub : U2 - 1;
    const int gA   = 2 * half;
    const int gB   = 2 * half + 1;

    float wA[U2], wB[U2];                    // 48 weight VGPRs
#pragma unroll
    for (int k = 0; k < U2; ++k) {
        wA[k] = Uo[k * G2 + gA * U2 + u];
        wB[k] = Uo[k * G2 + gB * U2 + u];
    }

    const int len = lengths[b];              // >= 1
    const float* Pb = P + (size_t)b * T_ * G2;

    float cu, hu;
    float pA[3], pB[3];
#pragma unroll
    for (int i = 0; i < 3; ++i) {
        const int ti = (i < len) ? i : len - 1;
        pA[i] = Pb[(size_t)ti * G2 + gA * U2 + u];
        pB[i] = Pb[(size_t)ti * G2 + gB * U2 + u];
    }

    // ---- peeled t = 0 (h == 0, c == 0) ----
    {
        const float zA = pA[0], zB = pB[0];
        const float oA = __shfl_xor(zA, 32);
        const float oB = __shfl_xor(zB, 32);
        const float z_i = half ? oA : zA;
        const float z_g = half ? zA : oA;
        const float z_o = half ? zB : oB;
        const float ig = sigmoidf_(z_i);
        const float gg = tanhf_fast(z_g);
        const float og = sigmoidf_(z_o);
        cu = ig * gg;                        // f*0 drops out
        hu = og * tanhf_fast(cu);
        pA[0] = pA[1]; pA[1] = pA[2];
        pB[0] = pB[1]; pB[1] = pB[2];
        const int tn = (3 < len) ? 3 : len - 1;
        pA[2] = Pb[(size_t)tn * G2 + gA * U2 + u];
        pB[2] = Pb[(size_t)tn * G2 + gB * U2 + u];
    }

    // ---- steady state t = 1..len-1: unconditional weight use ----
#pragma unroll 1
    for (int t = 1; t < len; ++t) {
        const int tn = (t + 3 < len) ? (t + 3) : (len - 1);
        const float pAn = Pb[(size_t)tn * G2 + gA * U2 + u];
        const float pBn = Pb[(size_t)tn * G2 + gB * U2 + u];

        float zA0 = pA[0], zA1 = 0.0f, zB0 = pB[0], zB1 = 0.0f;
#pragma unroll
        for (int k = 0; k < U2; ++k) {
            const float hk = __int_as_float(
                __builtin_amdgcn_readlane(__float_as_int(hu), k));   // uniform idx
            if (k & 1) { zA1 += hk * wA[k]; zB1 += hk * wB[k]; }
            else       { zA0 += hk * wA[k]; zB0 += hk * wB[k]; }
        }
        const float zA = zA0 + zA1;          // half0: z_i ; half1: z_g
        const float zB = zB0 + zB1;          // half0: z_f ; half1: z_o
        const float oA = __shfl_xor(zA, 32);
        const float oB = __shfl_xor(zB, 32);

        const float z_i = half ? oA : zA;
        const float z_f = half ? oB : zB;
        const float z_g = half ? zA : oA;
        const float z_o = half ? zB : oB;

        const float ig = sigmoidf_(z_i);
        const float fg = sigmoidf_(z_f);
        const float gg = tanhf_fast(z_g);
        const float og = sigmoidf_(z_o);
        cu = fg * cu + ig * gg;
        hu = og * tanhf_fast(cu);            // identical on both halves

        pA[0] = pA[1]; pA[1] = pA[2]; pA[2] = pAn;
        pB[0] = pB[1]; pB[1] = pB[2]; pB[2] = pBn;
    }

    float acc = bd[0];
#pragma unroll
    for (int k = 0; k < U2; ++k)
        acc += __int_as_float(__builtin_amdgcn_readlane(__float_as_int(hu), k)) * Wd[k];
    if (lane == 0) out[b] = sigmoidf_(acc);
}

// Fallback outer (feats path), peeled the same way.
__global__ __launch_bounds__(64, 1) void outer_kernel_f(
    const float* __restrict__ feats, const int* __restrict__ lengths,
    const float* __restrict__ Wo, const float* __restrict__ Uo,
    const float* __restrict__ bo, const float* __restrict__ Wd,
    const float* __restrict__ bd, float* __restrict__ out)
{
    const int b = blockIdx.x;
    const int lane = threadIdx.x;
    const int u = (lane < U2) ? lane : U2 - 1;

    float wu[4][U2], wx[4][U1], bz[4];
#pragma unroll
    for (int g = 0; g < 4; ++g) {
        bz[g] = bo[g * U2 + u];
#pragma unroll
        for (int k = 0; k < U2; ++k) wu[g][k] = Uo[k * G2 + g * U2 + u];
#pragma unroll
        for (int k = 0; k < U1; ++k) wx[g][k] = Wo[k * G2 + g * U2 + u];
    }

    const int len = lengths[b];
    const float* Fb = feats + (size_t)b * T_ * U1;
    float cu, hu;

    {   // t = 0 peeled
        float z[4];
#pragma unroll
        for (int g = 0; g < 4; ++g) z[g] = bz[g];
#pragma unroll
        for (int k = 0; k < U1; ++k) {
            const float fk = Fb[k];
#pragma unroll
            for (int g = 0; g < 4; ++g) z[g] += fk * wx[g][k];
        }
        const float ig = sigmoidf_(z[0]);
        const float gg = tanhf_fast(z[2]);
        const float og = sigmoidf_(z[3]);
        cu = ig * gg;
        hu = og * tanhf_fast(cu);
    }

#pragma unroll 1
    for (int t = 1; t < len; ++t) {
        float z[4];
#pragma unroll
        for (int g = 0; g < 4; ++g) z[g] = bz[g];
        const float* Ft = Fb + (size_t)t * U1;
#pragma unroll
        for (int k = 0; k < U1; ++k) {
            const float fk = Ft[k];
#pragma unroll
            for (int g = 0; g < 4; ++g) z[g] += fk * wx[g][k];
        }
#pragma unroll
        for (int k = 0; k < U2; ++k) {
            const float hk = __int_as_float(__builtin_amdgcn_readlane(__float_as_int(hu), k));
#pragma unroll
            for (int g = 0; g < 4; ++g) z[g] += hk * wu[g][k];
        }
        const float ig = sigmoidf_(z[0]);
        const float fg = sigmoidf_(z[1]);
        const float gg = tanhf_fast(z[2]);
        const float og = sigmoidf_(z[3]);
        cu = fg * cu + ig * gg;
        hu = og * tanhf_fast(cu);
    }

    float acc = bd[0];
#pragma unroll
    for (int k = 0; k < U2; ++k)
        acc += __int_as_float(__builtin_amdgcn_readlane(__float_as_int(hu), k)) * Wd[k];
    if (lane == 0) out[b] = sigmoidf_(acc);
}

extern "C" void kernel_launch(void* const* d_in, const int* in_sizes, int n_in,
                              void* d_out, int out_size, void* d_ws, size_t ws_size,
                              hipStream_t stream) {
    const float* x       = (const float*)d_in[0];
    const int*   lengths = (const int*)  d_in[1];
    const float* Wi      = (const float*)d_in[2];
    const float* Ui      = (const float*)d_in[3];
    const float* bi      = (const float*)d_in[4];
    const float* Wo      = (const float*)d_in[5];
    const float* Uo      = (const float*)d_in[6];
    const float* bo      = (const float*)d_in[7];
    const float* Wd      = (const float*)d_in[8];
    const float* bd      = (const float*)d_in[9];
    float* out = (float*)d_out;

    unsigned int* UiF = (unsigned int*)d_ws;
    unsigned int* WoF = UiF + 2048;
    float* data = (float*)((char*)d_ws + 16384);
    const size_t P_BYTES = (size_t)B_ * T_ * G2 * sizeof(float);   // 25.2 MB

    prep_frags<<<dim3(1), dim3(64), 0, stream>>>(Ui, Wo, UiF, WoF);

    if (ws_size >= 16384 + P_BYTES) {
        inner_kernel<true><<<dim3(B_ * T_ / 64), dim3(256), 0, stream>>>(
            x, lengths, Wi, bi, (const uint4*)UiF, (const uint4*)WoF, bo, data);
        outer_kernel_p<<<dim3(B_), dim3(64), 0, stream>>>(
            data, lengths, Uo, Wd, bd, out);
    } else {
        inner_kernel<false><<<dim3(B_ * T_ / 64), dim3(256), 0, stream>>>(
            x, lengths, Wi, bi, (const uint4*)UiF, (const uint4*)WoF, bo, data);
        outer_kernel_f<<<dim3(B_), dim3(64), 0, stream>>>(
            data, lengths, Wo, Uo, bo, Wd, bd, out);
    }
}

// Round 9
// 196.898 us; speedup vs baseline: 1.3217x; 1.0066x over previous
//
#include <hip/hip_runtime.h>

#define B_  256
#define T_  256
#define S_  20
#define U1  32
#define G1  128   // 4*U1
#define U2  24
#define G2  96    // 4*U2

typedef __attribute__((ext_vector_type(8))) short short8;   // 8 bf16 = 4 VGPRs
typedef __attribute__((ext_vector_type(4))) float f32x4;    // MFMA acc

// Raw-HW activations (v_exp_f32 = 2^x, pre-scaled by log2e). R7: ocml __expf
// -> these took outer 134->74us.
__device__ __forceinline__ float sigmoidf_(float x) {
    return __builtin_amdgcn_rcpf(1.0f + __builtin_amdgcn_exp2f(x * -1.44269504f));
}
__device__ __forceinline__ float tanhf_fast(float x) {   // 1 - 2/(1+e^{2x})
    return 1.0f - 2.0f * __builtin_amdgcn_rcpf(1.0f + __builtin_amdgcn_exp2f(x * 2.88539008f));
}

__device__ __forceinline__ unsigned short f2bf(float a) {
    unsigned int u = __float_as_uint(a);
    u += 0x7FFFu + ((u >> 16) & 1u);
    return (unsigned short)(u >> 16);
}
__device__ __forceinline__ unsigned int pack2bf(float a, float b) {
    unsigned int ua = __float_as_uint(a); ua += 0x7FFFu + ((ua >> 16) & 1u);
    unsigned int ub = __float_as_uint(b); ub += 0x7FFFu + ((ub >> 16) & 1u);
    return (ua >> 16) | (ub & 0xFFFF0000u);
}
union frag_u { short8 v; unsigned int u[4]; };

// Pre-swizzle Ui/Wo into MFMA B-fragment order (bf16 packed pairs).
__global__ void prep_frags(const float* __restrict__ Ui, const float* __restrict__ Wo,
                           unsigned int* __restrict__ UiF, unsigned int* __restrict__ WoF) {
    const int lane = threadIdx.x;     // 64
    const int q = lane >> 4, n = lane & 15;
#pragma unroll
    for (int tt = 0; tt < 8; ++tt)
#pragma unroll
        for (int k2 = 0; k2 < 4; ++k2) {
            const float e0 = Ui[(8 * q + 2 * k2) * G1 + 16 * tt + n];
            const float e1 = Ui[(8 * q + 2 * k2 + 1) * G1 + 16 * tt + n];
            UiF[(tt * 64 + lane) * 4 + k2] = pack2bf(e0, e1);
        }
#pragma unroll
    for (int tt = 0; tt < 6; ++tt)
#pragma unroll
        for (int k2 = 0; k2 < 4; ++k2) {
            const float e0 = Wo[(8 * q + 2 * k2) * G2 + 16 * tt + n];
            const float e1 = Wo[(8 * q + 2 * k2 + 1) * G2 + 16 * tt + n];
            WoF[(tt * 64 + lane) * 4 + k2] = pack2bf(e0, e1);
        }
}

// Inner LSTM via MFMA (bf16 in, fp32 acc). One wave = 16 t-rows x 32 units.
// amdgpu_waves_per_eu(2,2): tell the scheduler occupancy is FIXED at 2
// waves/EU so it stops pressure-minimizing (the default max-occupancy
// heuristic was sinking the Ui fragment loads into the s-loop -> per-step
// L2 refetch; launch_bounds' 2nd arg only sets the CAP, not the target).
template <bool WRITE_P>
__global__ __attribute__((amdgpu_flat_work_group_size(256, 256)))
__attribute__((amdgpu_waves_per_eu(2, 2)))
void inner_kernel(
    const float* __restrict__ x, const int* __restrict__ lengths,
    const float* __restrict__ Wi, const float* __restrict__ bi,
    const uint4* __restrict__ UiF, const uint4* __restrict__ WoF,
    const float* __restrict__ bo, float* __restrict__ outbuf)
{
    __shared__ float xs[4][320];
    __shared__ unsigned short hbb[4][16][40];
    const int lane = threadIdx.x & 63;
    const int w = __builtin_amdgcn_readfirstlane((int)(threadIdx.x >> 6));
    const int q = lane >> 4;
    const int n = lane & 15;
    const int tile = blockIdx.x & 3;
    const int b = blockIdx.x >> 2;
    const int len = lengths[b];
    const int wt0 = tile * 64 + w * 16;
    if (wt0 >= len) return;                     // wave-uniform exit, no barriers

    // stage x tile (320 contiguous floats, 5 coalesced loads)
    const float* xg = x + (size_t)(b * T_ + wt0) * S_;
#pragma unroll
    for (int i = 0; i < 5; ++i) xs[w][64 * i + lane] = xg[64 * i + lane];

    // Ui fragments: loaded once, resident (see waves_per_eu note)
    frag_u Bui[8];
#pragma unroll
    for (int tt = 0; tt < 8; ++tt) {
        uint4 v = UiF[tt * 64 + lane];
        Bui[tt].u[0] = v.x; Bui[tt].u[1] = v.y; Bui[tt].u[2] = v.z; Bui[tt].u[3] = v.w;
    }
    float bi_l[8], Wi_l[8];
#pragma unroll
    for (int tt = 0; tt < 8; ++tt) { bi_l[tt] = bi[16 * tt + n]; Wi_l[tt] = Wi[16 * tt + n]; }

    float c[2][4];
#pragma unroll
    for (int uh = 0; uh < 2; ++uh)
#pragma unroll
        for (int r = 0; r < 4; ++r) c[uh][r] = 0.0f;

    // ---- peeled s = 0 (h == 0: no MFMA) ----
    {
        float x0[4];
#pragma unroll
        for (int r = 0; r < 4; ++r) x0[r] = xs[w][(4 * q + r) * S_];
        f32x4 acc[8];
#pragma unroll
        for (int tt = 0; tt < 8; ++tt)
#pragma unroll
            for (int r = 0; r < 4; ++r)
                acc[tt][r] = bi_l[tt] + x0[r] * Wi_l[tt];
#pragma unroll
        for (int uh = 0; uh < 2; ++uh)
#pragma unroll
            for (int r = 0; r < 4; ++r) {
                const float iv = sigmoidf_(acc[0 + uh][r]);
                const float fv = sigmoidf_(acc[2 + uh][r]);
                const float gv = tanhf_fast(acc[4 + uh][r]);
                const float ov = sigmoidf_(acc[6 + uh][r]);
                c[uh][r] = fv * c[uh][r] + iv * gv;
                hbb[w][4 * q + r][n + 16 * uh] = f2bf(ov * tanhf_fast(c[uh][r]));
            }
    }

    // ---- steady state s = 1..19: unconditional MFMA ----
    float xc[4];
#pragma unroll
    for (int r = 0; r < 4; ++r) xc[r] = xs[w][(4 * q + r) * S_ + 1];

#pragma unroll 1
    for (int s = 1; s < S_; ++s) {
        const int sn = (s + 1 < S_) ? s + 1 : S_ - 1;
        float xnx[4];
#pragma unroll
        for (int r = 0; r < 4; ++r) xnx[r] = xs[w][(4 * q + r) * S_ + sn];

        f32x4 acc[8];
#pragma unroll
        for (int tt = 0; tt < 8; ++tt)
#pragma unroll
            for (int r = 0; r < 4; ++r)
                acc[tt][r] = bi_l[tt] + xc[r] * Wi_l[tt];

        const short8 A = *(const short8*)&hbb[w][n][8 * q];  // ds_read_b128
#pragma unroll
        for (int tt = 0; tt < 8; ++tt)
            acc[tt] = __builtin_amdgcn_mfma_f32_16x16x32_bf16(A, Bui[tt].v, acc[tt], 0, 0, 0);

#pragma unroll
        for (int uh = 0; uh < 2; ++uh)
#pragma unroll
            for (int r = 0; r < 4; ++r) {
                const float iv = sigmoidf_(acc[0 + uh][r]);
                const float fv = sigmoidf_(acc[2 + uh][r]);
                const float gv = tanhf_fast(acc[4 + uh][r]);
                const float ov = sigmoidf_(acc[6 + uh][r]);
                c[uh][r] = fv * c[uh][r] + iv * gv;
                hbb[w][4 * q + r][n + 16 * uh] = f2bf(ov * tanhf_fast(c[uh][r]));
            }
#pragma unroll
        for (int r = 0; r < 4; ++r) xc[r] = xnx[r];
    }

    if constexpr (WRITE_P) {
        frag_u Bwo[6];
#pragma unroll
        for (int tt = 0; tt < 6; ++tt) {
            uint4 v = WoF[tt * 64 + lane];
            Bwo[tt].u[0] = v.x; Bwo[tt].u[1] = v.y; Bwo[tt].u[2] = v.z; Bwo[tt].u[3] = v.w;
        }
        const short8 A = *(const short8*)&hbb[w][n][8 * q];
        f32x4 accp[6];
#pragma unroll
        for (int tt = 0; tt < 6; ++tt) {
            const float bv = bo[16 * tt + n];
#pragma unroll
            for (int r = 0; r < 4; ++r) accp[tt][r] = bv;
            accp[tt] = __builtin_amdgcn_mfma_f32_16x16x32_bf16(A, Bwo[tt].v, accp[tt], 0, 0, 0);
        }
#pragma unroll
        for (int r = 0; r < 4; ++r) {
            const int t_row = wt0 + 4 * q + r;
            if (t_row < len) {
                float* Pr = outbuf + (size_t)(b * T_ + t_row) * G2 + n;
#pragma unroll
                for (int tt = 0; tt < 6; ++tt) Pr[16 * tt] = accp[tt][r];
            }
        }
    } else {
#pragma unroll
        for (int r = 0; r < 4; ++r) {
            const int t_row = wt0 + 4 * q + r;
            if (t_row < len) {
                float* Fr = outbuf + (size_t)(b * T_ + t_row) * U1;
#pragma unroll
                for (int uh = 0; uh < 2; ++uh)
                    Fr[n + 16 * uh] = __uint_as_float((unsigned)hbb[w][4 * q + r][n + 16 * uh] << 16);
            }
        }
    }
}

// Outer LSTM + head: 1 wave/seq, gate-split across wave halves (half 0:
// gates i,f; half 1: g,o; 48 weight VGPRs/lane). amdgpu_waves_per_eu(1,1):
// occupancy is 1 wave/CU anyway; pinning max=1 stops the scheduler's
// max-occupancy heuristic from sinking the 48 loop-invariant weight loads
// into the 256-step serial loop (R7/R8: VGPR=36, ~48 L2 loads/step,
// ~690 cyc/step). readlane h-broadcast; 2 shfl_xor to swap z halves.
__global__ __attribute__((amdgpu_flat_work_group_size(64, 64)))
__attribute__((amdgpu_waves_per_eu(1, 1)))
void outer_kernel_p(
    const float* __restrict__ P,        // [B*T*G2]
    const int*   __restrict__ lengths,  // [B]
    const float* __restrict__ Uo,       // [U2*G2]
    const float* __restrict__ Wd,       // [U2]
    const float* __restrict__ bd,       // [1]
    float* __restrict__ out)            // [B]
{
    const int b = blockIdx.x;
    const int lane = threadIdx.x;
    const int half = lane >> 5;              // 0: gates i,f  1: gates g,o
    const int sub  = lane & 31;
    const int u    = (sub < U2) ? sub : U2 - 1;
    const int gA   = 2 * half;
    const int gB   = 2 * half + 1;

    float wA[U2], wB[U2];                    // 48 weight VGPRs, resident
#pragma unroll
    for (int k = 0; k < U2; ++k) {
        wA[k] = Uo[k * G2 + gA * U2 + u];
        wB[k] = Uo[k * G2 + gB * U2 + u];
    }

    const int len = lengths[b];              // >= 1
    const float* Pb = P + (size_t)b * T_ * G2;

    float cu, hu;
    float pA[3], pB[3];
#pragma unroll
    for (int i = 0; i < 3; ++i) {
        const int ti = (i < len) ? i : len - 1;
        pA[i] = Pb[(size_t)ti * G2 + gA * U2 + u];
        pB[i] = Pb[(size_t)ti * G2 + gB * U2 + u];
    }

    // ---- peeled t = 0 (h == 0, c == 0) ----
    {
        const float zA = pA[0], zB = pB[0];
        const float oA = __shfl_xor(zA, 32);
        const float oB = __shfl_xor(zB, 32);
        const float z_i = half ? oA : zA;
        const float z_g = half ? zA : oA;
        const float z_o = half ? zB : oB;
        const float ig = sigmoidf_(z_i);
        const float gg = tanhf_fast(z_g);
        const float og = sigmoidf_(z_o);
        cu = ig * gg;                        // f*0 drops out
        hu = og * tanhf_fast(cu);
        pA[0] = pA[1]; pA[1] = pA[2];
        pB[0] = pB[1]; pB[1] = pB[2];
        const int tn = (3 < len) ? 3 : len - 1;
        pA[2] = Pb[(size_t)tn * G2 + gA * U2 + u];
        pB[2] = Pb[(size_t)tn * G2 + gB * U2 + u];
    }

    // ---- steady state t = 1..len-1 ----
#pragma unroll 1
    for (int t = 1; t < len; ++t) {
        const int tn = (t + 3 < len) ? (t + 3) : (len - 1);
        const float pAn = Pb[(size_t)tn * G2 + gA * U2 + u];
        const float pBn = Pb[(size_t)tn * G2 + gB * U2 + u];

        float zA0 = pA[0], zA1 = 0.0f, zB0 = pB[0], zB1 = 0.0f;
#pragma unroll
        for (int k = 0; k < U2; ++k) {
            const float hk = __int_as_float(
                __builtin_amdgcn_readlane(__float_as_int(hu), k));   // uniform idx
            if (k & 1) { zA1 += hk * wA[k]; zB1 += hk * wB[k]; }
            else       { zA0 += hk * wA[k]; zB0 += hk * wB[k]; }
        }
        const float zA = zA0 + zA1;          // half0: z_i ; half1: z_g
        const float zB = zB0 + zB1;          // half0: z_f ; half1: z_o
        const float oA = __shfl_xor(zA, 32);
        const float oB = __shfl_xor(zB, 32);

        const float z_i = half ? oA : zA;
        const float z_f = half ? oB : zB;
        const float z_g = half ? zA : oA;
        const float z_o = half ? zB : oB;

        const float ig = sigmoidf_(z_i);
        const float fg = sigmoidf_(z_f);
        const float gg = tanhf_fast(z_g);
        const float og = sigmoidf_(z_o);
        cu = fg * cu + ig * gg;
        hu = og * tanhf_fast(cu);            // identical on both halves

        pA[0] = pA[1]; pA[1] = pA[2]; pA[2] = pAn;
        pB[0] = pB[1]; pB[1] = pB[2]; pB[2] = pBn;
    }

    float acc = bd[0];
#pragma unroll
    for (int k = 0; k < U2; ++k)
        acc += __int_as_float(__builtin_amdgcn_readlane(__float_as_int(hu), k)) * Wd[k];
    if (lane == 0) out[b] = sigmoidf_(acc);
}

// Fallback outer (feats path), same occupancy pinning.
__global__ __attribute__((amdgpu_flat_work_group_size(64, 64)))
__attribute__((amdgpu_waves_per_eu(1, 1)))
void outer_kernel_f(
    const float* __restrict__ feats, const int* __restrict__ lengths,
    const float* __restrict__ Wo, const float* __restrict__ Uo,
    const float* __restrict__ bo, const float* __restrict__ Wd,
    const float* __restrict__ bd, float* __restrict__ out)
{
    const int b = blockIdx.x;
    const int lane = threadIdx.x;
    const int u = (lane < U2) ? lane : U2 - 1;

    float wu[4][U2], wx[4][U1], bz[4];
#pragma unroll
    for (int g = 0; g < 4; ++g) {
        bz[g] = bo[g * U2 + u];
#pragma unroll
        for (int k = 0; k < U2; ++k) wu[g][k] = Uo[k * G2 + g * U2 + u];
#pragma unroll
        for (int k = 0; k < U1; ++k) wx[g][k] = Wo[k * G2 + g * U2 + u];
    }

    const int len = lengths[b];
    const float* Fb = feats + (size_t)b * T_ * U1;
    float cu, hu;

    {   // t = 0 peeled
        float z[4];
#pragma unroll
        for (int g = 0; g < 4; ++g) z[g] = bz[g];
#pragma unroll
        for (int k = 0; k < U1; ++k) {
            const float fk = Fb[k];
#pragma unroll
            for (int g = 0; g < 4; ++g) z[g] += fk * wx[g][k];
        }
        const float ig = sigmoidf_(z[0]);
        const float gg = tanhf_fast(z[2]);
        const float og = sigmoidf_(z[3]);
        cu = ig * gg;
        hu = og * tanhf_fast(cu);
    }

#pragma unroll 1
    for (int t = 1; t < len; ++t) {
        float z[4];
#pragma unroll
        for (int g = 0; g < 4; ++g) z[g] = bz[g];
        const float* Ft = Fb + (size_t)t * U1;
#pragma unroll
        for (int k = 0; k < U1; ++k) {
            const float fk = Ft[k];
#pragma unroll
            for (int g = 0; g < 4; ++g) z[g] += fk * wx[g][k];
        }
#pragma unroll
        for (int k = 0; k < U2; ++k) {
            const float hk = __int_as_float(__builtin_amdgcn_readlane(__float_as_int(hu), k));
#pragma unroll
            for (int g = 0; g < 4; ++g) z[g] += hk * wu[g][k];
        }
        const float ig = sigmoidf_(z[0]);
        const float fg = sigmoidf_(z[1]);
        const float gg = tanhf_fast(z[2]);
        const float og = sigmoidf_(z[3]);
        cu = fg * cu + ig * gg;
        hu = og * tanhf_fast(cu);
    }

    float acc = bd[0];
#pragma unroll
    for (int k = 0; k < U2; ++k)
        acc += __int_as_float(__builtin_amdgcn_readlane(__float_as_int(hu), k)) * Wd[k];
    if (lane == 0) out[b] = sigmoidf_(acc);
}

extern "C" void kernel_launch(void* const* d_in, const int* in_sizes, int n_in,
                              void* d_out, int out_size, void* d_ws, size_t ws_size,
                              hipStream_t stream) {
    const float* x       = (const float*)d_in[0];
    const int*   lengths = (const int*)  d_in[1];
    const float* Wi      = (const float*)d_in[2];
    const float* Ui      = (const float*)d_in[3];
    const float* bi      = (const float*)d_in[4];
    const float* Wo      = (const float*)d_in[5];
    const float* Uo      = (const float*)d_in[6];
    const float* bo      = (const float*)d_in[7];
    const float* Wd      = (const float*)d_in[8];
    const float* bd      = (const float*)d_in[9];
    float* out = (float*)d_out;

    unsigned int* UiF = (unsigned int*)d_ws;
    unsigned int* WoF = UiF + 2048;
    float* data = (float*)((char*)d_ws + 16384);
    const size_t P_BYTES = (size_t)B_ * T_ * G2 * sizeof(float);   // 25.2 MB

    prep_frags<<<dim3(1), dim3(64), 0, stream>>>(Ui, Wo, UiF, WoF);

    if (ws_size >= 16384 + P_BYTES) {
        inner_kernel<true><<<dim3(B_ * T_ / 64), dim3(256), 0, stream>>>(
            x, lengths, Wi, bi, (const uint4*)UiF, (const uint4*)WoF, bo, data);
        outer_kernel_p<<<dim3(B_), dim3(64), 0, stream>>>(
            data, lengths, Uo, Wd, bd, out);
    } else {
        inner_kernel<false><<<dim3(B_ * T_ / 64), dim3(256), 0, stream>>>(
            x, lengths, Wi, bi, (const uint4*)UiF, (const uint4*)WoF, bo, data);
        outer_kernel_f<<<dim3(B_), dim3(64), 0, stream>>>(
            data, lengths, Wo, Uo, bo, Wd, bd, out);
    }
}